// Round 8
// baseline (336.183 us; speedup 1.0000x reference)
//
#include <hip/hip_runtime.h>
#include <hip/hip_fp16.h>
#include <math.h>

#define N_NODES 50000
#define N_EDGES 1600000
#define D_INF   128
#define D_HID   64
#define BN_EPS  1e-5f
#define NBINS   391      // fine bins, 128 nodes each (bin = dst >> 7)  [R3/R6 best]
#define BINCAP  4608     // per-bin cap (mean 4092, +8 sigma)
#define EPB     6250     // edges per binA block (256 blocks x 6250 = E)
#define GEMM1B  3125     // gemm1 blocks inside k_pre
#define NPAIR   3125     // gather block-pairs (16 nodes each, layer-2)
#define NCOPY   64       // BN stat accumulator copies (atomic spread)

// ============ fused k_pre: blocks 0..255 binA | 256..3380 gemm1 ============
// Ledger: 391 bins > 782 (R6: smaller bins -> partial-line writes, +7us).
// R4: direct per-node CSR scatter = 8x XCD write amplification (19MB array);
// deg[] here is 200KB -> amplification negligible, 32 adds/addr = throughput
// regime (R1 law: serialization only at >>100 adds/addr).
// R5: no grid.sync megakernels (XCD L2 flush doubles HBM traffic).
// gemm1 writes SPLIT half-tables ha (cols 0-31) / hb (cols 32-63), RAW
// (dinv now folded into csr weights, not tables).
struct SmGemm { float sw[D_INF * D_HID]; float sx[16 * D_INF]; };  // 40 KB
struct SmBin  { int hcnt[NBINS]; int hbase[NBINS]; };              // 3.1 KB
union SmPre { SmGemm g; SmBin a; };

__global__ __launch_bounds__(256) void k_pre(const float* __restrict__ wsc,
                                             const float* __restrict__ wfc,
                                             const int*   __restrict__ ei,
                                             const float* __restrict__ alpha,
                                             int* __restrict__ bin_cur,
                                             unsigned long long* __restrict__ binned,
                                             float* __restrict__ deg,
                                             const float* __restrict__ x,
                                             const float* __restrict__ W,
                                             __half* __restrict__ ha,
                                             __half* __restrict__ hb) {
    __shared__ SmPre sm;
    int t = threadIdx.x;
    if (blockIdx.x < 256) {
        // ---------------- binA: bin edges by dst>>7, staged coalesced ------
        int e0 = blockIdx.x * EPB;
        for (int b = t; b < NBINS; b += 256) sm.a.hcnt[b] = 0;
        __syncthreads();
        for (int i = t; i < EPB; i += 256)
            atomicAdd(&sm.a.hcnt[ei[N_EDGES + e0 + i] >> 7], 1);
        __syncthreads();
        for (int b = t; b < NBINS; b += 256) {
            int c = sm.a.hcnt[b];
            sm.a.hbase[b] = c ? atomicAdd(&bin_cur[b], c) : 0;
            sm.a.hcnt[b] = 0;
        }
        __syncthreads();
        float a = 1.0f / (1.0f + expf(-alpha[0]));
        for (int i = t; i < EPB; i += 256) {
            int e = e0 + i;
            int s = ei[e], d = ei[N_EDGES + e];
            float wm = fmaf(a, wsc[e] - wfc[e], wfc[e]);   // a*wsc+(1-a)*wfc
            atomicAdd(&deg[d], wm);                        // fire-and-forget
            int bin = d >> 7;
            int slot = atomicAdd(&sm.a.hcnt[bin], 1);
            int gpos = sm.a.hbase[bin] + slot;
            if (gpos < BINCAP) {
                unsigned long long ent =
                    ((unsigned long long)__float_as_uint(wm) << 32)
                    | (unsigned int)(s | ((d & 127) << 16));
                binned[(size_t)bin * BINCAP + gpos] = ent;
            }
        }
    } else {
        // ---------------- gemm1: [N,128]x[128,64] -> fp16 halves -----------
        int row0 = (blockIdx.x - 256) * 16;
#pragma unroll
        for (int j = 0; j < 32; ++j) sm.g.sw[t + j * 256] = W[t + j * 256];
#pragma unroll
        for (int j = 0; j < 8; ++j) {
            int i = t + j * 256;
            int r = i >> 7, k = i & 127;
            sm.g.sx[i] = x[(row0 + r) * D_INF + k];
        }
        __syncthreads();
        int c = t & 63, rg = (t >> 6) * 4;
        float a0 = 0, a1 = 0, a2 = 0, a3 = 0;
#pragma unroll 4
        for (int k = 0; k < D_INF; ++k) {
            float w = sm.g.sw[k * D_HID + c];
            a0 = fmaf(sm.g.sx[(rg + 0) * D_INF + k], w, a0);
            a1 = fmaf(sm.g.sx[(rg + 1) * D_INF + k], w, a1);
            a2 = fmaf(sm.g.sx[(rg + 2) * D_INF + k], w, a2);
            a3 = fmaf(sm.g.sx[(rg + 3) * D_INF + k], w, a3);
        }
        __half* tbl = (c < 32) ? ha : hb;
        int cc = c & 31;
        tbl[(row0 + rg + 0) * 32 + cc] = __float2half_rn(a0);
        tbl[(row0 + rg + 1) * 32 + cc] = __float2half_rn(a1);
        tbl[(row0 + rg + 2) * 32 + cc] = __float2half_rn(a2);
        tbl[(row0 + rg + 3) * 32 + cc] = __float2half_rn(a3);
    }
}

__device__ inline float hdec(unsigned int u) {
    return __half2float(__ushort_as_half((unsigned short)(u >> 16)));
}

// ====== k_fused (512 thr, one block per bin): binB + gather-1 merged. ======
// The binB->gather1 grid dependency was ONLY the dinv fold into h tables;
// with deg[] accumulated in k_pre, dinv[src] folds into the csr WEIGHT at
// fill time (rsqrt on the fly; deg 200KB = L2-resident read-only), h tables
// stay raw, and everything gather-1 needs (csr, row starts, counts, dinv)
// is block-local: csr kept in LDS, no h-scale pass, no boundary.
// BN stats: per-thread reg accumulation over the block's 128 nodes, one
// LDS reduce, spread atomics (R1 law).
// LDS 56KB -> 2 blocks/CU co-resident (covers the 391/256 makespan split).
__global__ __launch_bounds__(512) void k_fused(const int* __restrict__ bin_cur,
                                               const unsigned long long* __restrict__ binned,
                                               const float* __restrict__ deg,
                                               int2*  __restrict__ row_se,
                                               float* __restrict__ dinv,
                                               const __half* __restrict__ ha,
                                               const __half* __restrict__ hb,
                                               unsigned int* __restrict__ csr,
                                               const float* __restrict__ bias,
                                               float* __restrict__ out,
                                               float* __restrict__ stat) {
    __shared__ union {
        unsigned long long stage[BINCAP];                  // 36.9 KB (phase 1)
        struct { float s1[512]; float s2[512]; } r;        // 4 KB (epilogue)
    } u;
    __shared__ unsigned int csr_l[BINCAP];                 // 18.4 KB
    __shared__ int   ncnt[128];
    __shared__ int   sscan[128];
    __shared__ int   lbl[128];
    __shared__ float sdinv[128];
    int t = threadIdx.x;
    int bin = blockIdx.x;
    int node0 = bin << 7;
    int nnodes = min(128, N_NODES - node0);
    if (t < 128) ncnt[t] = 0;
    int cntb = min(bin_cur[bin], BINCAP);
    const unsigned long long* mybin = binned + (size_t)bin * BINCAP;
    for (int i = t; i < cntb; i += 512) u.stage[i] = mybin[i];
    __syncthreads();
    // ---- pass 1: per-node counts (int LDS atomic; ndeg no longer needed)
    for (int i = t; i < cntb; i += 512)
        atomicAdd(&ncnt[((unsigned int)u.stage[i] >> 16) & 127], 1);
    __syncthreads();
    if (t < 128) {
        float dv = rsqrtf(1.0f + ((t < nnodes) ? deg[node0 + t] : 0.0f));
        sdinv[t] = dv;
        if (t < nnodes) dinv[node0 + t] = dv;
        sscan[t] = ncnt[t];
    }
    __syncthreads();
    for (int off = 1; off < 128; off <<= 1) {
        int v2 = (t >= off && t < 128) ? sscan[t - off] : 0;
        __syncthreads();
        if (t < 128) sscan[t] += v2;
        __syncthreads();
    }
    if (t < 128) {
        int lb = sscan[t] - ncnt[t];
        lbl[t] = lb;
        if (t < nnodes) {
            int g0 = bin * BINCAP + lb;
            row_se[node0 + t] = make_int2(g0, g0 + ncnt[t]);
        }
    }
    __syncthreads();
    if (t < 128) ncnt[t] = 0;   // reuse as fill cursor (ends == count again)
    __syncthreads();
    // ---- fill: csr entry = src | fp16(wm * dinv[src]); LDS + global copy
    unsigned int* gcsr = csr + (size_t)bin * BINCAP;
    for (int i = t; i < cntb; i += 512) {
        unsigned long long ent = u.stage[i];
        unsigned int lo = (unsigned int)ent;
        int nl  = (lo >> 16) & 127;
        int src = lo & 0xFFFFu;
        float wm = __uint_as_float((unsigned int)(ent >> 32));
        float ds = rsqrtf(1.0f + deg[src]);                // L2-hot 200KB
        int slot = atomicAdd(&ncnt[nl], 1);
        int pos = lbl[nl] + slot;
        unsigned short wh = __half_as_ushort(__float2half_rn(wm * ds));
        unsigned int w = (unsigned int)src | ((unsigned int)wh << 16);
        csr_l[pos] = w;
        gcsr[pos] = w;
    }
    __syncthreads();
    // ---- gather-1 for this bin's nodes (R3 geometry: 32-lane group per
    // node-half; cq=ln&3 picks a float4 of the 64B row, sg=ln>>2 the edge).
    // csr words read straight from LDS (4 same-addr lanes broadcast).
    int g  = t >> 5;           // 0..15: group; parity = table half
    int ln = t & 31;
    int sg = ln >> 2, cq = ln & 3;
    int h  = g & 1;
    const float4* __restrict__ h4 = (const float4*)(h ? hb : ha);
    float accS[8], accQ[8];
#pragma unroll
    for (int i = 0; i < 8; ++i) { accS[i] = 0.0f; accQ[i] = 0.0f; }
    int nvh = nnodes * 2;
    for (int vh = g; vh < nvh; vh += 16) {
        int nloc = vh >> 1;
        int node = node0 + nloc;
        float dd = sdinv[nloc];
        int s0 = lbl[nloc];
        int s1e = s0 + ncnt[nloc];
        float acc[8];
        if (sg == 0) {         // self term: dd * h_raw, added once
            float4 sv = h4[node * 4 + cq];
            const __half2* p = reinterpret_cast<const __half2*>(&sv);
#pragma unroll
            for (int i = 0; i < 4; ++i) {
                float2 f = __half22float2(p[i]);
                acc[2 * i] = f.x * dd; acc[2 * i + 1] = f.y * dd;
            }
        } else {
#pragma unroll
            for (int i = 0; i < 8; ++i) acc[i] = 0.0f;
        }
        for (int b = s0; b < s1e; b += 32) {
            int c0 = min(32, s1e - b);
            int cm = c0 - 1;
            unsigned int u0 = csr_l[b + min(sg,      cm)];
            unsigned int u1 = csr_l[b + min(sg + 8,  cm)];
            unsigned int u2 = csr_l[b + min(sg + 16, cm)];
            unsigned int u3 = csr_l[b + min(sg + 24, cm)];
            float4 r0 = h4[(u0 & 0xFFFFu) * 4 + cq];
            float4 r1 = h4[(u1 & 0xFFFFu) * 4 + cq];
            float4 r2 = h4[(u2 & 0xFFFFu) * 4 + cq];
            float4 r3 = h4[(u3 & 0xFFFFu) * 4 + cq];
            float w0 = (sg      < c0) ? hdec(u0) : 0.0f;
            float w1 = (sg + 8  < c0) ? hdec(u1) : 0.0f;
            float w2 = (sg + 16 < c0) ? hdec(u2) : 0.0f;
            float w3 = (sg + 24 < c0) ? hdec(u3) : 0.0f;
            const __half2* p0 = reinterpret_cast<const __half2*>(&r0);
            const __half2* p1 = reinterpret_cast<const __half2*>(&r1);
            const __half2* p2 = reinterpret_cast<const __half2*>(&r2);
            const __half2* p3 = reinterpret_cast<const __half2*>(&r3);
#pragma unroll
            for (int i = 0; i < 4; ++i) {
                float2 f0 = __half22float2(p0[i]);
                float2 f1 = __half22float2(p1[i]);
                float2 f2 = __half22float2(p2[i]);
                float2 f3 = __half22float2(p3[i]);
                acc[2*i]   = fmaf(f0.x, w0, acc[2*i]);
                acc[2*i+1] = fmaf(f0.y, w0, acc[2*i+1]);
                acc[2*i]   = fmaf(f1.x, w1, acc[2*i]);
                acc[2*i+1] = fmaf(f1.y, w1, acc[2*i+1]);
                acc[2*i]   = fmaf(f2.x, w2, acc[2*i]);
                acc[2*i+1] = fmaf(f2.y, w2, acc[2*i+1]);
                acc[2*i]   = fmaf(f3.x, w3, acc[2*i]);
                acc[2*i+1] = fmaf(f3.y, w3, acc[2*i+1]);
            }
        }
#pragma unroll
        for (int off = 16; off >= 4; off >>= 1) {
#pragma unroll
            for (int i = 0; i < 8; ++i) acc[i] += __shfl_down(acc[i], off, 32);
        }
        if (ln < 4) {
            int col0 = h * 32 + cq * 8;
            float v[8];
#pragma unroll
            for (int i = 0; i < 8; ++i) v[i] = fmaf(acc[i], dd, bias[col0 + i]);
            float4* o = (float4*)out;
            o[node * 16 + h * 8 + cq * 2]     = make_float4(v[0], v[1], v[2], v[3]);
            o[node * 16 + h * 8 + cq * 2 + 1] = make_float4(v[4], v[5], v[6], v[7]);
#pragma unroll
            for (int i = 0; i < 8; ++i) { accS[i] += v[i]; accQ[i] += v[i] * v[i]; }
        }
    }
    __syncthreads();   // stage dead; overlay r.s1/s2
    if (ln < 4) {
#pragma unroll
        for (int i = 0; i < 8; ++i) {
            u.r.s1[g * 32 + cq * 8 + i] = accS[i];
            u.r.s2[g * 32 + cq * 8 + i] = accQ[i];
        }
    }
    __syncthreads();
    if (t < 64) {      // col = t; half = t>>5; groups of same parity
        int hh = t >> 5, c32 = t & 31;
        float s = 0.0f, q = 0.0f;
#pragma unroll
        for (int k = 0; k < 8; ++k) {
            s += u.r.s1[(2 * k + hh) * 32 + c32];
            q += u.r.s2[(2 * k + hh) * 32 + c32];
        }
        int cp = bin & (NCOPY - 1);
        atomicAdd(&stat[cp * 128 + t],      s);
        atomicAdd(&stat[cp * 128 + 64 + t], q);
    }
}

// == gather layer-2 (512 thr, R3 body): csr weights now carry dinv[src];
// tables raw -> self term multiplied by dd. ==================================
__global__ __launch_bounds__(512) void k_gather(const __half* __restrict__ ha,
                                                const __half* __restrict__ hb,
                                                const unsigned int* __restrict__ csr,
                                                const int2*  __restrict__ row_se,
                                                const float* __restrict__ dinv,
                                                const float* __restrict__ bias,
                                                float* __restrict__ out,
                                                float* __restrict__ stat) {
    __shared__ float s1[512], s2[512];
    int t = threadIdx.x;
    int half = blockIdx.x & 1;
    const float4* __restrict__ h4 = (const float4*)(half ? hb : ha);
    int node = (blockIdx.x >> 1) * 16 + (t >> 5);
    int ln = t & 31;
    int sg = ln >> 2;     // 0..7: edge subgroup
    int cq = ln & 3;      // 0..3: column quad (8 cols = 16B)
    int2 se = row_se[node];
    float dd = dinv[node];
    float acc[8];
    if (sg == 0) {        // self term: dd * h_raw, added once
        float4 sv = h4[node * 4 + cq];
        const __half2* p = reinterpret_cast<const __half2*>(&sv);
#pragma unroll
        for (int i = 0; i < 4; ++i) {
            float2 f = __half22float2(p[i]);
            acc[2 * i] = f.x * dd; acc[2 * i + 1] = f.y * dd;
        }
    } else {
#pragma unroll
        for (int i = 0; i < 8; ++i) acc[i] = 0.0f;
    }
    for (int b = se.x; b < se.y; b += 32) {
        int c0 = min(32, se.y - b);
        int cm = c0 - 1;
        unsigned int my = (ln < c0) ? csr[b + ln] : 0u;
        unsigned int u0 = __shfl(my, min(sg,      cm), 32);
        unsigned int u1 = __shfl(my, min(sg + 8,  cm), 32);
        unsigned int u2 = __shfl(my, min(sg + 16, cm), 32);
        unsigned int u3 = __shfl(my, min(sg + 24, cm), 32);
        float4 r0 = h4[(u0 & 0xFFFFu) * 4 + cq];
        float4 r1 = h4[(u1 & 0xFFFFu) * 4 + cq];
        float4 r2 = h4[(u2 & 0xFFFFu) * 4 + cq];
        float4 r3 = h4[(u3 & 0xFFFFu) * 4 + cq];
        float w0 = (sg      < c0) ? hdec(u0) : 0.0f;
        float w1 = (sg + 8  < c0) ? hdec(u1) : 0.0f;
        float w2 = (sg + 16 < c0) ? hdec(u2) : 0.0f;
        float w3 = (sg + 24 < c0) ? hdec(u3) : 0.0f;
        const __half2* p0 = reinterpret_cast<const __half2*>(&r0);
        const __half2* p1 = reinterpret_cast<const __half2*>(&r1);
        const __half2* p2 = reinterpret_cast<const __half2*>(&r2);
        const __half2* p3 = reinterpret_cast<const __half2*>(&r3);
#pragma unroll
        for (int i = 0; i < 4; ++i) {
            float2 f0 = __half22float2(p0[i]);
            float2 f1 = __half22float2(p1[i]);
            float2 f2 = __half22float2(p2[i]);
            float2 f3 = __half22float2(p3[i]);
            acc[2*i]   = fmaf(f0.x, w0, acc[2*i]);
            acc[2*i+1] = fmaf(f0.y, w0, acc[2*i+1]);
            acc[2*i]   = fmaf(f1.x, w1, acc[2*i]);
            acc[2*i+1] = fmaf(f1.y, w1, acc[2*i+1]);
            acc[2*i]   = fmaf(f2.x, w2, acc[2*i]);
            acc[2*i+1] = fmaf(f2.y, w2, acc[2*i+1]);
            acc[2*i]   = fmaf(f3.x, w3, acc[2*i]);
            acc[2*i+1] = fmaf(f3.y, w3, acc[2*i+1]);
        }
    }
#pragma unroll
    for (int off = 16; off >= 4; off >>= 1) {
#pragma unroll
        for (int i = 0; i < 8; ++i) acc[i] += __shfl_down(acc[i], off, 32);
    }
    if (ln < 4) {
        int col0 = half * 32 + cq * 8;
        float v[8];
#pragma unroll
        for (int i = 0; i < 8; ++i) v[i] = fmaf(acc[i], dd, bias[col0 + i]);
        float4* o = (float4*)out;
        o[node * 16 + half * 8 + cq * 2]     = make_float4(v[0], v[1], v[2], v[3]);
        o[node * 16 + half * 8 + cq * 2 + 1] = make_float4(v[4], v[5], v[6], v[7]);
        int lb = (t >> 5) * 32 + cq * 8;
#pragma unroll
        for (int i = 0; i < 8; ++i) { s1[lb + i] = v[i]; s2[lb + i] = v[i] * v[i]; }
    }
    __syncthreads();
#pragma unroll
    for (int off = 256; off >= 32; off >>= 1) {
        if (t < off) { s1[t] += s1[t + off]; s2[t] += s2[t + off]; }
        __syncthreads();
    }
    if (t < 32) {
        int cp = (blockIdx.x >> 1) & (NCOPY - 1);
        int col = half * 32 + t;
        atomicAdd(&stat[cp * 128 + col],      s1[t]);
        atomicAdd(&stat[cp * 128 + 64 + col], s2[t]);
    }
}

// == GEMM2 fused BN1+ReLU in, RAW split fp16 out: [N,64]x[64,64] ============
// dinv no longer folded here (csr weights carry dinv[src]).
__global__ __launch_bounds__(256) void k_gemm2_bn(const float* __restrict__ hin,
                                                  const float* __restrict__ stat,
                                                  const float* __restrict__ gamma,
                                                  const float* __restrict__ beta,
                                                  const float* __restrict__ W,
                                                  __half* __restrict__ ha,
                                                  __half* __restrict__ hb) {
    __shared__ float sw[D_HID * D_HID];   // 16 KB
    __shared__ float sx[16 * D_HID];      // 4 KB
    __shared__ float sc[D_HID], sh[D_HID];
    int t = threadIdx.x;
    int row0 = blockIdx.x * 16;
#pragma unroll
    for (int j = 0; j < 16; ++j) sw[t + j * 256] = W[t + j * 256];
    if (t < 64) {
        float s = 0.0f, q = 0.0f;
#pragma unroll 8
        for (int c = 0; c < NCOPY; ++c) {
            s += stat[c * 128 + t];
            q += stat[c * 128 + 64 + t];
        }
        const float invn = 1.0f / (float)N_NODES;
        float mean = s * invn;
        float var  = q * invn - mean * mean;   // biased, = jnp.var
        float g    = gamma[t] * rsqrtf(var + BN_EPS);
        sc[t] = g;
        sh[t] = beta[t] - mean * g;
    }
    __syncthreads();
#pragma unroll
    for (int j = 0; j < 4; ++j) {
        int i = t + j * 256;
        int k = i & 63;
        sx[i] = fmaxf(0.0f, fmaf(hin[row0 * D_HID + i], sc[k], sh[k]));
    }
    __syncthreads();
    int c = t & 63, rg = (t >> 6) * 4;
    float a0 = 0, a1 = 0, a2 = 0, a3 = 0;
#pragma unroll 4
    for (int k = 0; k < D_HID; ++k) {
        float w = sw[k * D_HID + c];
        a0 = fmaf(sx[(rg + 0) * D_HID + k], w, a0);
        a1 = fmaf(sx[(rg + 1) * D_HID + k], w, a1);
        a2 = fmaf(sx[(rg + 2) * D_HID + k], w, a2);
        a3 = fmaf(sx[(rg + 3) * D_HID + k], w, a3);
    }
    __half* tbl = (c < 32) ? ha : hb;
    int cc = c & 31;
    tbl[(row0 + rg + 0) * 32 + cc] = __float2half_rn(a0);
    tbl[(row0 + rg + 1) * 32 + cc] = __float2half_rn(a1);
    tbl[(row0 + rg + 2) * 32 + cc] = __float2half_rn(a2);
    tbl[(row0 + rg + 3) * 32 + cc] = __float2half_rn(a3);
}

// ====== BN apply + ReLU (in place, float4); coeffs from spread stats =======
__global__ __launch_bounds__(256) void k_bn_apply_relu(float4* __restrict__ h,
                                                       const float* __restrict__ stat,
                                                       const float* __restrict__ gamma,
                                                       const float* __restrict__ beta) {
    __shared__ float sc[D_HID], sh[D_HID];
    int t = threadIdx.x;
    if (t < 64) {
        float s = 0.0f, q = 0.0f;
#pragma unroll 8
        for (int c = 0; c < NCOPY; ++c) {
            s += stat[c * 128 + t];
            q += stat[c * 128 + 64 + t];
        }
        const float invn = 1.0f / (float)N_NODES;
        float mean = s * invn;
        float var  = q * invn - mean * mean;
        float g    = gamma[t] * rsqrtf(var + BN_EPS);
        sc[t] = g;
        sh[t] = beta[t] - mean * g;
    }
    __syncthreads();
    int idx = blockIdx.x * 256 + t;
    if (idx >= N_NODES * D_HID / 4) return;
    int j = (idx & 15) * 4;
    float4 v = h[idx];
    v.x = fmaxf(0.0f, fmaf(v.x, sc[j],     sh[j]));
    v.y = fmaxf(0.0f, fmaf(v.y, sc[j + 1], sh[j + 1]));
    v.z = fmaxf(0.0f, fmaf(v.z, sc[j + 2], sh[j + 2]));
    v.w = fmaxf(0.0f, fmaf(v.w, sc[j + 3], sh[j + 3]));
    h[idx] = v;
}

extern "C" void kernel_launch(void* const* d_in, const int* in_sizes, int n_in,
                              void* d_out, int out_size, void* d_ws, size_t ws_size,
                              hipStream_t stream) {
    const float* x     = (const float*)d_in[0];
    const int*   ei_sc = (const int*)  d_in[1];   // [2*E] src then dst
    const float* w_sc  = (const float*)d_in[2];
    const float* w_fc  = (const float*)d_in[4];
    const float* alpha = (const float*)d_in[5];
    const float* W1    = (const float*)d_in[6];
    const float* b1    = (const float*)d_in[7];
    const float* W2    = (const float*)d_in[8];
    const float* b2    = (const float*)d_in[9];
    const float* g1    = (const float*)d_in[10];
    const float* be1   = (const float*)d_in[11];
    const float* g2    = (const float*)d_in[12];
    const float* be2   = (const float*)d_in[13];
    float* out = (float*)d_out;

    // ---- workspace layout, all segments 16B-aligned: ~41.7 MB
    // binned | row_se | bin_cur(400) | stats | deg | dinv | csr | ha | hb | agg
    unsigned long long* binned = (unsigned long long*)d_ws;        // NBINS*BINCAP u64
    int2*  row_se  = (int2*)(binned + (size_t)NBINS * BINCAP);     // N int2
    int*   bin_cur = (int*)(row_se + N_NODES);                     // 400 (391 used)
    float* stats   = (float*)(bin_cur + 400);                      // 2*NCOPY*128
    float* deg     = stats + 2 * NCOPY * 128;                      // N
    float* dinv    = deg + N_NODES;                                // N
    unsigned int* csr = (unsigned int*)(dinv + N_NODES);           // NBINS*BINCAP
    __half* ha     = (__half*)(csr + (size_t)NBINS * BINCAP);      // N*32 halves
    __half* hb     = ha + (size_t)N_NODES * 32;                    // N*32 halves
    float* agg     = (float*)(hb + (size_t)N_NODES * 32);          // N*64

    const int gV4 = (N_NODES * D_HID / 4 + 255) / 256;             // 3125
    const int gGA = NPAIR * 2;                                     // 6250
    const int gGM = N_NODES / 16;                                  // 3125

    // ---- one memset covers bin_cur + both stat layers + deg (contiguous)
    hipMemsetAsync(bin_cur, 0, (400 + 2 * NCOPY * 128 + N_NODES) * sizeof(int),
                   stream);
    // ---- binA (+deg atomics) + gemm1
    k_pre  <<<256 + GEMM1B, 256, 0, stream>>>(w_sc, w_fc, ei_sc, alpha,
                                              bin_cur, binned, deg, x, W1, ha, hb);
    // ---- CSR build (dinv[src] folded into weights) + layer-1 gather + BN1 stats
    k_fused<<<NBINS, 512, 0, stream>>>(bin_cur, binned, deg, row_se, dinv,
                                       ha, hb, csr, b1, agg, stats);
    // ---- layer 2
    k_gemm2_bn<<<gGM, 256, 0, stream>>>(agg, stats, g1, be1, W2, ha, hb);
    k_gather  <<<gGA, 512, 0, stream>>>(ha, hb, csr, row_se, dinv, b2, out,
                                        stats + NCOPY * 128);
    k_bn_apply_relu<<<gV4, 256, 0, stream>>>((float4*)out, stats + NCOPY * 128,
                                             g2, be2);
}

// Round 9
// 296.483 us; speedup vs baseline: 1.1339x; 1.1339x over previous
//
#include <hip/hip_runtime.h>
#include <hip/hip_fp16.h>
#include <math.h>

#define N_NODES 50000
#define N_EDGES 1600000
#define D_INF   128
#define D_HID   64
#define BN_EPS  1e-5f
#define NBINS   391      // fine bins, 128 nodes each (bin = dst >> 7)  [R3/R6 best]
#define BINCAP  4608     // per-bin csr cap (mean 4092, +8 sigma)
#define CAPB    44       // per-(bin,block) slice cap; Poisson(16)+7sig, P(ovf)~5e-4
#define SLOTS   (256 * CAPB)   // 11264 slots per bin (incl. holes)
#define EPB     6250     // edges per binA block (256 blocks x 6250 = E)
#define GEMM1B  3125     // gemm1 blocks inside k_pre
#define NPAIR   3125     // gather block-pairs (16 nodes each)
#define NCOPY   64       // BN stat accumulator copies (atomic spread)

// ============ fused k_pre: blocks 0..255 binA | 256..3380 gemm1 ============
// R9: SINGLE-PASS binA with deterministic per-(bin,block) slices -- kills
// the hist pass (dst re-read + 1.6M LDS atomics + global reservation) AND
// the memset dispatch (no bin_cur; cnt fully overwritten; stats zeroed by
// gemm1 blocks below). Entry split u32(src|fp16 wm) + u8(dst&127) keeps
// slice runs line-dense (R4/R6 write-amplification lessons; R8: random-
// address device-scope atomics cost ~32B HBM each -- never again).
struct SmGemm { float sw[D_INF * D_HID]; float sx[16 * D_INF]; };  // 40 KB
struct SmBin  { int ncur[NBINS]; };                                // 1.6 KB
union SmPre { SmGemm g; SmBin a; };

__global__ __launch_bounds__(256) void k_pre(const float* __restrict__ wsc,
                                             const float* __restrict__ wfc,
                                             const int*   __restrict__ ei,
                                             const float* __restrict__ alpha,
                                             unsigned short* __restrict__ cnt,
                                             unsigned int*  __restrict__ b32,
                                             unsigned char* __restrict__ b8,
                                             const float* __restrict__ x,
                                             const float* __restrict__ W,
                                             __half* __restrict__ ha,
                                             __half* __restrict__ hb,
                                             float* __restrict__ stats) {
    __shared__ SmPre sm;
    int t = threadIdx.x;
    if (blockIdx.x < 256) {
        int blk = blockIdx.x;
        for (int b = t; b < NBINS; b += 256) sm.a.ncur[b] = 0;
        __syncthreads();
        float a = 1.0f / (1.0f + expf(-alpha[0]));
        int e0 = blk * EPB;
        for (int i = t; i < EPB; i += 256) {
            int e = e0 + i;
            int s = ei[e], d = ei[N_EDGES + e];
            float wm = fmaf(a, wsc[e] - wfc[e], wfc[e]);   // a*wsc+(1-a)*wfc
            int bin = d >> 7;
            int slot = atomicAdd(&sm.a.ncur[bin], 1);
            if (slot < CAPB) {
                size_t p = (size_t)bin * SLOTS + blk * CAPB + slot;
                unsigned short wh = __half_as_ushort(__float2half_rn(wm));
                b32[p] = (unsigned int)s | ((unsigned int)wh << 16);
                b8[p]  = (unsigned char)(d & 127);
            }
        }
        __syncthreads();
        for (int b = t; b < NBINS; b += 256)
            cnt[blk * NBINS + b] = (unsigned short)min(sm.a.ncur[b], CAPB);
    } else {
        // ---- stats-zero prologue (replaces the memset dispatch): first 32
        // gemm1 blocks clear both layers' spread accumulators (2*64*128).
        int gb = blockIdx.x - 256;
        if (gb < 32) {
            int o = gb * 512 + t;
            stats[o] = 0.0f;
            stats[o + 256] = 0.0f;
        }
        // ---------------- gemm1: [N,128]x[128,64] -> fp16 halves -----------
        int row0 = gb * 16;
#pragma unroll
        for (int j = 0; j < 32; ++j) sm.g.sw[t + j * 256] = W[t + j * 256];
#pragma unroll
        for (int j = 0; j < 8; ++j) {
            int i = t + j * 256;
            int r = i >> 7, k = i & 127;
            sm.g.sx[i] = x[(row0 + r) * D_INF + k];
        }
        __syncthreads();
        int c = t & 63, rg = (t >> 6) * 4;
        float a0 = 0, a1 = 0, a2 = 0, a3 = 0;
#pragma unroll 4
        for (int k = 0; k < D_INF; ++k) {
            float w = sm.g.sw[k * D_HID + c];
            a0 = fmaf(sm.g.sx[(rg + 0) * D_INF + k], w, a0);
            a1 = fmaf(sm.g.sx[(rg + 1) * D_INF + k], w, a1);
            a2 = fmaf(sm.g.sx[(rg + 2) * D_INF + k], w, a2);
            a3 = fmaf(sm.g.sx[(rg + 3) * D_INF + k], w, a3);
        }
        __half* tbl = (c < 32) ? ha : hb;
        int cc = c & 31;
        tbl[(row0 + rg + 0) * 32 + cc] = __float2half_rn(a0);
        tbl[(row0 + rg + 1) * 32 + cc] = __float2half_rn(a1);
        tbl[(row0 + rg + 2) * 32 + cc] = __float2half_rn(a2);
        tbl[(row0 + rg + 3) * 32 + cc] = __float2half_rn(a3);
    }
}

// ====== phase B (512 thr): stage holey slices once (wide uint4 loads);
// hist -> dinv, row_se; scale h by dinv; fill csr (pure permutation of the
// staged u32 entries -- wm already fp16 inside). R7's packed-u64 hist kept.
__global__ __launch_bounds__(512) void k_binB(const unsigned short* __restrict__ cnt,
                                              const unsigned int*  __restrict__ b32,
                                              const unsigned char* __restrict__ b8,
                                              int2*  __restrict__ row_se,
                                              float* __restrict__ dinv,
                                              __half* __restrict__ ha,
                                              __half* __restrict__ hb,
                                              unsigned int* __restrict__ csr) {
    __shared__ unsigned int  st32[SLOTS];          // 45 KB
    __shared__ unsigned char st8[SLOTS];           // 11 KB
    __shared__ unsigned short scnt[256];
    __shared__ unsigned long long nacc[128];       // count<<48 | fixed ndeg
    __shared__ int   ncnt[128];
    __shared__ int   sscan[128];
    __shared__ int   lb[128];
    __shared__ float sdinv[128];
    int t = threadIdx.x;
    int bin = blockIdx.x;
    if (t < 256) scnt[t] = cnt[t * NBINS + bin];
    if (t < 128) nacc[t] = 0ULL;
    size_t base = (size_t)bin * SLOTS;
    {   // wide stage: uint4 for b32, uint for b8 (both 16B/4B aligned)
        const uint4* g4 = (const uint4*)(b32 + base);
        uint4* s4 = (uint4*)st32;
        for (int i = t; i < SLOTS / 4; i += 512) s4[i] = g4[i];
        const unsigned int* g1 = (const unsigned int*)(b8 + base);
        unsigned int* s1w = (unsigned int*)st8;
        for (int i = t; i < SLOTS / 4; i += 512) s1w[i] = g1[i];
    }
    __syncthreads();
    // ---- pass 1: per-node count+ndeg via one packed u64 LDS atomic
    for (int i = t; i < SLOTS; i += 512) {
        int seg = i / CAPB;
        if (i - seg * CAPB < (int)scnt[seg]) {
            float wm = __half2float(__ushort_as_half((unsigned short)(st32[i] >> 16)));
            atomicAdd(&nacc[st8[i]],
                      (1ULL << 48) | (unsigned long long)(wm * 4294967296.0f));
        }
    }
    __syncthreads();
    int node0 = bin << 7;
    int nnodes = min(128, N_NODES - node0);
    if (t < 128) {
        unsigned long long v = nacc[t];
        int c = (int)(v >> 48);
        float nd = (float)(v & 0xFFFFFFFFFFFFULL) * 2.3283064365386963e-10f;
        float dv = rsqrtf(1.0f + nd);   // +1 self loop
        sdinv[t] = dv;
        if (t < nnodes) dinv[node0 + t] = dv;
        ncnt[t] = c;
        sscan[t] = c;
    }
    __syncthreads();
    for (int off = 1; off < 128; off <<= 1) {
        int u = (t >= off && t < 128) ? sscan[t - off] : 0;
        __syncthreads();
        if (t < 128) sscan[t] += u;
        __syncthreads();
    }
    if (t < 128) {
        int l = sscan[t] - ncnt[t];
        lb[t] = l;
        if (t < nnodes) {
            int s0 = min(l, BINCAP);
            int s1 = min(l + ncnt[t], BINCAP);
            row_se[node0 + t] = make_int2(bin * BINCAP + s0, bin * BINCAP + s1);
        }
    }
    __syncthreads();
    // ---- scale this bin's h rows by dinv (vectorized __half2)
    int nh = nnodes * 16;   // 16 half2 per table row
    __half2* pa = (__half2*)ha;
    __half2* pb = (__half2*)hb;
    for (int i = t; i < nh; i += 512) {
        int n = i >> 4;
        float dv = sdinv[n];
        int idx = node0 * 16 + i;
        float2 fa = __half22float2(pa[idx]);
        float2 fb = __half22float2(pb[idx]);
        pa[idx] = __floats2half2_rn(fa.x * dv, fa.y * dv);
        pb[idx] = __floats2half2_rn(fb.x * dv, fb.y * dv);
    }
    if (t < 128) ncnt[t] = 0;   // reuse as fill cursor
    __syncthreads();
    // ---- fill: csr = permutation of staged u32 entries
    for (int i = t; i < SLOTS; i += 512) {
        int seg = i / CAPB;
        if (i - seg * CAPB < (int)scnt[seg]) {
            int nl = st8[i];
            int slot = atomicAdd(&ncnt[nl], 1);
            int pos = lb[nl] + slot;
            if (pos < BINCAP) csr[bin * BINCAP + pos] = st32[i];
        }
    }
}

__device__ inline float hdec(unsigned int u) {
    return __half2float(__ushort_as_half((unsigned short)(u >> 16)));
}

// == gather (512 thr, R3/R7-verbatim): WIDE 16B/lane table reads (123->38us
// measured). cq=ln&3 picks a float4 (8 halves) of the 64B row; sg=ln>>2
// picks the edge -> 8 edges per load step, 4 lane-addresses/edge.
// BN stats: block LDS reduce -> atomics spread over NCOPY copies (R1 law).
// out[d] = dd * ( sum_e wm_e * h'[s_e] + h'[d] ) + bias   (h' = dinv*h)
__global__ __launch_bounds__(512) void k_gather(const __half* __restrict__ ha,
                                                const __half* __restrict__ hb,
                                                const unsigned int* __restrict__ csr,
                                                const int2*  __restrict__ row_se,
                                                const float* __restrict__ dinv,
                                                const float* __restrict__ bias,
                                                float* __restrict__ out,
                                                float* __restrict__ stat) {
    __shared__ float s1[512], s2[512];
    int t = threadIdx.x;
    int half = blockIdx.x & 1;
    const float4* __restrict__ h4 = (const float4*)(half ? hb : ha);
    int node = (blockIdx.x >> 1) * 16 + (t >> 5);
    int ln = t & 31;
    int sg = ln >> 2;     // 0..7: edge subgroup
    int cq = ln & 3;      // 0..3: column quad (8 cols = 16B)
    int2 se = row_se[node];
    float dd = dinv[node];
    float acc[8];
    if (sg == 0) {        // self term (pre-scaled by dinv), added once
        float4 sv = h4[node * 4 + cq];
        const __half2* p = reinterpret_cast<const __half2*>(&sv);
#pragma unroll
        for (int i = 0; i < 4; ++i) {
            float2 f = __half22float2(p[i]);
            acc[2 * i] = f.x; acc[2 * i + 1] = f.y;
        }
    } else {
#pragma unroll
        for (int i = 0; i < 8; ++i) acc[i] = 0.0f;
    }
    for (int b = se.x; b < se.y; b += 32) {
        int c0 = min(32, se.y - b);
        int cm = c0 - 1;
        unsigned int my = (ln < c0) ? csr[b + ln] : 0u;
        unsigned int u0 = __shfl(my, min(sg,      cm), 32);
        unsigned int u1 = __shfl(my, min(sg + 8,  cm), 32);
        unsigned int u2 = __shfl(my, min(sg + 16, cm), 32);
        unsigned int u3 = __shfl(my, min(sg + 24, cm), 32);
        float4 r0 = h4[(u0 & 0xFFFFu) * 4 + cq];
        float4 r1 = h4[(u1 & 0xFFFFu) * 4 + cq];
        float4 r2 = h4[(u2 & 0xFFFFu) * 4 + cq];
        float4 r3 = h4[(u3 & 0xFFFFu) * 4 + cq];
        float w0 = (sg      < c0) ? hdec(u0) : 0.0f;
        float w1 = (sg + 8  < c0) ? hdec(u1) : 0.0f;
        float w2 = (sg + 16 < c0) ? hdec(u2) : 0.0f;
        float w3 = (sg + 24 < c0) ? hdec(u3) : 0.0f;
        const __half2* p0 = reinterpret_cast<const __half2*>(&r0);
        const __half2* p1 = reinterpret_cast<const __half2*>(&r1);
        const __half2* p2 = reinterpret_cast<const __half2*>(&r2);
        const __half2* p3 = reinterpret_cast<const __half2*>(&r3);
#pragma unroll
        for (int i = 0; i < 4; ++i) {
            float2 f0 = __half22float2(p0[i]);
            float2 f1 = __half22float2(p1[i]);
            float2 f2 = __half22float2(p2[i]);
            float2 f3 = __half22float2(p3[i]);
            acc[2*i]   = fmaf(f0.x, w0, acc[2*i]);
            acc[2*i+1] = fmaf(f0.y, w0, acc[2*i+1]);
            acc[2*i]   = fmaf(f1.x, w1, acc[2*i]);
            acc[2*i+1] = fmaf(f1.y, w1, acc[2*i+1]);
            acc[2*i]   = fmaf(f2.x, w2, acc[2*i]);
            acc[2*i+1] = fmaf(f2.y, w2, acc[2*i+1]);
            acc[2*i]   = fmaf(f3.x, w3, acc[2*i]);
            acc[2*i+1] = fmaf(f3.y, w3, acc[2*i+1]);
        }
    }
#pragma unroll
    for (int off = 16; off >= 4; off >>= 1) {
#pragma unroll
        for (int i = 0; i < 8; ++i) acc[i] += __shfl_down(acc[i], off, 32);
    }
    if (ln < 4) {
        int col0 = half * 32 + cq * 8;
        float v[8];
#pragma unroll
        for (int i = 0; i < 8; ++i) v[i] = fmaf(acc[i], dd, bias[col0 + i]);
        float4* o = (float4*)out;
        o[node * 16 + half * 8 + cq * 2]     = make_float4(v[0], v[1], v[2], v[3]);
        o[node * 16 + half * 8 + cq * 2 + 1] = make_float4(v[4], v[5], v[6], v[7]);
        int lbx = (t >> 5) * 32 + cq * 8;
#pragma unroll
        for (int i = 0; i < 8; ++i) { s1[lbx + i] = v[i]; s2[lbx + i] = v[i] * v[i]; }
    }
    __syncthreads();
#pragma unroll
    for (int off = 256; off >= 32; off >>= 1) {
        if (t < off) { s1[t] += s1[t + off]; s2[t] += s2[t + off]; }
        __syncthreads();
    }
    if (t < 32) {
        int cp = (blockIdx.x >> 1) & (NCOPY - 1);
        int col = half * 32 + t;
        atomicAdd(&stat[cp * 128 + col],      s1[t]);
        atomicAdd(&stat[cp * 128 + 64 + col], s2[t]);
    }
}

// == GEMM2 fused BN1+ReLU in, dinv-scaled split fp16 out: [N,64]x[64,64] ====
// BN scale/shift computed inline from NCOPY-spread stat accumulators.
__global__ __launch_bounds__(256) void k_gemm2_bn(const float* __restrict__ hin,
                                                  const float* __restrict__ stat,
                                                  const float* __restrict__ gamma,
                                                  const float* __restrict__ beta,
                                                  const float* __restrict__ W,
                                                  const float* __restrict__ dinv,
                                                  __half* __restrict__ ha,
                                                  __half* __restrict__ hb) {
    __shared__ float sw[D_HID * D_HID];   // 16 KB
    __shared__ float sx[16 * D_HID];      // 4 KB
    __shared__ float sc[D_HID], sh[D_HID];
    int t = threadIdx.x;
    int row0 = blockIdx.x * 16;
#pragma unroll
    for (int j = 0; j < 16; ++j) sw[t + j * 256] = W[t + j * 256];
    if (t < 64) {
        float s = 0.0f, q = 0.0f;
#pragma unroll 8
        for (int c = 0; c < NCOPY; ++c) {
            s += stat[c * 128 + t];
            q += stat[c * 128 + 64 + t];
        }
        const float invn = 1.0f / (float)N_NODES;
        float mean = s * invn;
        float var  = q * invn - mean * mean;   // biased, = jnp.var
        float g    = gamma[t] * rsqrtf(var + BN_EPS);
        sc[t] = g;
        sh[t] = beta[t] - mean * g;
    }
    __syncthreads();
#pragma unroll
    for (int j = 0; j < 4; ++j) {
        int i = t + j * 256;
        int k = i & 63;
        sx[i] = fmaxf(0.0f, fmaf(hin[row0 * D_HID + i], sc[k], sh[k]));
    }
    __syncthreads();
    int c = t & 63, rg = (t >> 6) * 4;
    float a0 = 0, a1 = 0, a2 = 0, a3 = 0;
#pragma unroll 4
    for (int k = 0; k < D_HID; ++k) {
        float w = sw[k * D_HID + c];
        a0 = fmaf(sx[(rg + 0) * D_HID + k], w, a0);
        a1 = fmaf(sx[(rg + 1) * D_HID + k], w, a1);
        a2 = fmaf(sx[(rg + 2) * D_HID + k], w, a2);
        a3 = fmaf(sx[(rg + 3) * D_HID + k], w, a3);
    }
    __half* tbl = (c < 32) ? ha : hb;
    int cc = c & 31;
    tbl[(row0 + rg + 0) * 32 + cc] = __float2half_rn(a0 * dinv[row0 + rg + 0]);
    tbl[(row0 + rg + 1) * 32 + cc] = __float2half_rn(a1 * dinv[row0 + rg + 1]);
    tbl[(row0 + rg + 2) * 32 + cc] = __float2half_rn(a2 * dinv[row0 + rg + 2]);
    tbl[(row0 + rg + 3) * 32 + cc] = __float2half_rn(a3 * dinv[row0 + rg + 3]);
}

// ====== BN apply + ReLU (in place, float4); coeffs from spread stats =======
__global__ __launch_bounds__(256) void k_bn_apply_relu(float4* __restrict__ h,
                                                       const float* __restrict__ stat,
                                                       const float* __restrict__ gamma,
                                                       const float* __restrict__ beta) {
    __shared__ float sc[D_HID], sh[D_HID];
    int t = threadIdx.x;
    if (t < 64) {
        float s = 0.0f, q = 0.0f;
#pragma unroll 8
        for (int c = 0; c < NCOPY; ++c) {
            s += stat[c * 128 + t];
            q += stat[c * 128 + 64 + t];
        }
        const float invn = 1.0f / (float)N_NODES;
        float mean = s * invn;
        float var  = q * invn - mean * mean;
        float g    = gamma[t] * rsqrtf(var + BN_EPS);
        sc[t] = g;
        sh[t] = beta[t] - mean * g;
    }
    __syncthreads();
    int idx = blockIdx.x * 256 + t;
    if (idx >= N_NODES * D_HID / 4) return;
    int j = (idx & 15) * 4;
    float4 v = h[idx];
    v.x = fmaxf(0.0f, fmaf(v.x, sc[j],     sh[j]));
    v.y = fmaxf(0.0f, fmaf(v.y, sc[j + 1], sh[j + 1]));
    v.z = fmaxf(0.0f, fmaf(v.z, sc[j + 2], sh[j + 2]));
    v.w = fmaxf(0.0f, fmaf(v.w, sc[j + 3], sh[j + 3]));
    h[idx] = v;
}

extern "C" void kernel_launch(void* const* d_in, const int* in_sizes, int n_in,
                              void* d_out, int out_size, void* d_ws, size_t ws_size,
                              hipStream_t stream) {
    const float* x     = (const float*)d_in[0];
    const int*   ei_sc = (const int*)  d_in[1];   // [2*E] src then dst
    const float* w_sc  = (const float*)d_in[2];
    const float* w_fc  = (const float*)d_in[4];
    const float* alpha = (const float*)d_in[5];
    const float* W1    = (const float*)d_in[6];
    const float* b1    = (const float*)d_in[7];
    const float* W2    = (const float*)d_in[8];
    const float* b2    = (const float*)d_in[9];
    const float* g1    = (const float*)d_in[10];
    const float* be1   = (const float*)d_in[11];
    const float* g2    = (const float*)d_in[12];
    const float* be2   = (const float*)d_in[13];
    float* out = (float*)d_out;

    // ---- workspace layout, 16B-aligned, peak ~36.5 MB.
    // agg ALIASES binned32 (disjoint lifetimes: binned32 dead after k_binB,
    // agg born at gather1). Region sized max(17.6, 12.8) = binned32 size.
    const size_t NSLOT = (size_t)NBINS * SLOTS;                    // 4,404,224
    unsigned int* b32 = (unsigned int*)d_ws;                       // 17.6 MB
    float* agg = (float*)d_ws;                                     // 12.8 MB (alias)
    unsigned int* csr = b32 + NSLOT;                               // 7.2 MB
    __half* ha  = (__half*)(csr + (size_t)NBINS * BINCAP);         // 3.2 MB
    __half* hb  = ha + (size_t)N_NODES * 32;                       // 3.2 MB
    int2*  row_se = (int2*)(hb + (size_t)N_NODES * 32);            // 0.4 MB
    float* dinv   = (float*)(row_se + N_NODES);                    // 0.2 MB
    float* stats  = dinv + N_NODES;                                // 64 KB
    unsigned short* cnt = (unsigned short*)(stats + 2 * NCOPY * 128); // 200 KB
    unsigned char* b8 = (unsigned char*)(cnt + 256 * NBINS);       // 4.4 MB

    const int gV4 = (N_NODES * D_HID / 4 + 255) / 256;             // 3125
    const int gGA = NPAIR * 2;                                     // 6250
    const int gGM = N_NODES / 16;                                  // 3125

    // ---- no memset: cnt fully overwritten by binA; stats zeroed by the
    // first 32 gemm1 blocks inside k_pre; dinv/row_se fully written by binB.
    k_pre <<<256 + GEMM1B, 256, 0, stream>>>(w_sc, w_fc, ei_sc, alpha,
                                             cnt, b32, b8, x, W1, ha, hb, stats);
    k_binB<<<NBINS, 512, 0, stream>>>(cnt, b32, b8, row_se, dinv, ha, hb, csr);

    // ---- layer 1 (BN stats spread-atomic accumulated in gather epilogue)
    k_gather  <<<gGA, 512, 0, stream>>>(ha, hb, csr, row_se, dinv, b1, agg, stats);

    // ---- layer 2 (BN1+ReLU coeffs computed inline; dinv folded into output)
    k_gemm2_bn<<<gGM, 256, 0, stream>>>(agg, stats, g1, be1, W2, dinv, ha, hb);
    k_gather  <<<gGA, 512, 0, stream>>>(ha, hb, csr, row_se, dinv, b2, out,
                                        stats + NCOPY * 128);
    k_bn_apply_relu<<<gV4, 256, 0, stream>>>((float4*)out, stats + NCOPY * 128,
                                             g2, be2);
}

// Round 10
// 271.686 us; speedup vs baseline: 1.2374x; 1.0913x over previous
//
#include <hip/hip_runtime.h>
#include <hip/hip_fp16.h>
#include <math.h>

#define N_NODES 50000
#define N_EDGES 1600000
#define D_INF   128
#define D_HID   64
#define BN_EPS  1e-5f
#define NBINS   256      // R10: 256 balanced bins (1 binB block per CU)
#define NPB     196      // nodes per bin (256*196 = 50176 >= N)
#define BINCAP  6912     // per-bin cap (mean 6250, +8.4 sigma)
#define EPB     6250     // edges per binA block (256 blocks x 6250 = E)
#define GEMM1B  3125     // gemm1 blocks inside k_pre
#define NPAIR   3125     // gather block-pairs (16 nodes each)
#define NCOPY   64       // BN stat accumulator copies (atomic spread)

// ============ fused k_pre: blocks 0..255 binA | 256..3380 gemm1 ============
// Ledger: reserved-contiguous-run binned writes are the density optimum
// (R4: direct scatter = 8x XCD write amp; R6: small bins = partial lines;
// R9: fixed slices = cross-XCD false sharing). R5: no grid.sync mega
// (XCD L2 flush doubles HBM traffic). R8: random-address device atomics
// cost ~32B HBM each. R10: 256 bins x 196 nodes -- bigger runs (~195B),
// binB perfectly CU-balanced. binA hist = 2KB LDS.
struct SmGemm { float sw[D_INF * D_HID]; float sx[16 * D_INF]; };  // 40 KB
struct SmBin  { int hcnt[NBINS]; int hbase[NBINS]; };              // 2 KB
union SmPre { SmGemm g; SmBin a; };

__global__ __launch_bounds__(256) void k_pre(const float* __restrict__ wsc,
                                             const float* __restrict__ wfc,
                                             const int*   __restrict__ ei,
                                             const float* __restrict__ alpha,
                                             int* __restrict__ bin_cur,
                                             unsigned long long* __restrict__ binned,
                                             const float* __restrict__ x,
                                             const float* __restrict__ W,
                                             __half* __restrict__ ha,
                                             __half* __restrict__ hb) {
    __shared__ SmPre sm;
    int t = threadIdx.x;
    if (blockIdx.x < 256) {
        // ---------------- binA: bin edges by dst/196, staged coalesced -----
        int e0 = blockIdx.x * EPB;
        sm.a.hcnt[t] = 0;
        __syncthreads();
        for (int i = t; i < EPB; i += 256)
            atomicAdd(&sm.a.hcnt[(unsigned)ei[N_EDGES + e0 + i] / NPB], 1);
        __syncthreads();
        {
            int c = sm.a.hcnt[t];
            sm.a.hbase[t] = c ? atomicAdd(&bin_cur[t], c) : 0;
            sm.a.hcnt[t] = 0;
        }
        __syncthreads();
        float a = 1.0f / (1.0f + expf(-alpha[0]));
        for (int i = t; i < EPB; i += 256) {
            int e = e0 + i;
            int s = ei[e], d = ei[N_EDGES + e];
            float wm = fmaf(a, wsc[e] - wfc[e], wfc[e]);   // a*wsc+(1-a)*wfc
            int bin = (unsigned)d / NPB;
            int loc = d - bin * NPB;                       // 0..195, 8 bits
            int slot = atomicAdd(&sm.a.hcnt[bin], 1);
            int gpos = sm.a.hbase[bin] + slot;
            if (gpos < BINCAP) {
                unsigned long long ent =
                    ((unsigned long long)__float_as_uint(wm) << 32)
                    | (unsigned int)(s | (loc << 16));
                binned[(size_t)bin * BINCAP + gpos] = ent;
            }
        }
    } else {
        // ---------------- gemm1: [N,128]x[128,64] -> fp16 halves -----------
        int row0 = (blockIdx.x - 256) * 16;
#pragma unroll
        for (int j = 0; j < 32; ++j) sm.g.sw[t + j * 256] = W[t + j * 256];
#pragma unroll
        for (int j = 0; j < 8; ++j) {
            int i = t + j * 256;
            int r = i >> 7, k = i & 127;
            sm.g.sx[i] = x[(row0 + r) * D_INF + k];
        }
        __syncthreads();
        int c = t & 63, rg = (t >> 6) * 4;
        float a0 = 0, a1 = 0, a2 = 0, a3 = 0;
#pragma unroll 4
        for (int k = 0; k < D_INF; ++k) {
            float w = sm.g.sw[k * D_HID + c];
            a0 = fmaf(sm.g.sx[(rg + 0) * D_INF + k], w, a0);
            a1 = fmaf(sm.g.sx[(rg + 1) * D_INF + k], w, a1);
            a2 = fmaf(sm.g.sx[(rg + 2) * D_INF + k], w, a2);
            a3 = fmaf(sm.g.sx[(rg + 3) * D_INF + k], w, a3);
        }
        __half* tbl = (c < 32) ? ha : hb;
        int cc = c & 31;
        tbl[(row0 + rg + 0) * 32 + cc] = __float2half_rn(a0);
        tbl[(row0 + rg + 1) * 32 + cc] = __float2half_rn(a1);
        tbl[(row0 + rg + 2) * 32 + cc] = __float2half_rn(a2);
        tbl[(row0 + rg + 3) * 32 + cc] = __float2half_rn(a3);
    }
}

// ====== merged phase B (512 thr, 256 balanced blocks = 1/CU): LDS-stage
// entries once; packed-u64 hist -> dinv, row_se; scale h by dinv; fill csr.
// R7's one-atomic pass-1 kept (count<<48 | wm in 2^-32 fixed point; max
// 6912*2^32 = 2^44.8 < 2^48, no overflow; ~1e-8 deg quantization).
// R10 kills the 391-on-256 makespan quantization (135 CUs ran 2 blocks,
// 121 idle half the kernel). LDS ~62 KB.
__global__ __launch_bounds__(512) void k_binB(const int* __restrict__ bin_cur,
                                              const unsigned long long* __restrict__ binned,
                                              int2*  __restrict__ row_se,
                                              float* __restrict__ dinv,
                                              __half* __restrict__ ha,
                                              __half* __restrict__ hb,
                                              unsigned int* __restrict__ csr) {
    __shared__ unsigned long long stage[BINCAP];   // 55.3 KB
    __shared__ unsigned long long nacc[256];       // count<<48 | fixed ndeg
    __shared__ int   ncnt[256];
    __shared__ int   sscan[256];
    __shared__ float sdinv[256];
    __shared__ int   lb[256];
    int t = threadIdx.x;
    int bin = blockIdx.x;
    if (t < 256) nacc[t] = 0ULL;
    int cnt = min(bin_cur[bin], BINCAP);
    const unsigned long long* mybin = binned + (size_t)bin * BINCAP;
    for (int i = t; i < cnt; i += 512) stage[i] = mybin[i];
    __syncthreads();
    for (int i = t; i < cnt; i += 512) {
        unsigned long long ent = stage[i];
        unsigned int lo = (unsigned int)ent;
        int nl = (lo >> 16) & 255;
        float wm = __uint_as_float((unsigned int)(ent >> 32));
        unsigned long long pk = (1ULL << 48)
            | (unsigned long long)(wm * 4294967296.0f);
        atomicAdd(&nacc[nl], pk);
    }
    __syncthreads();
    int node0 = bin * NPB;
    int nnodes = min(NPB, N_NODES - node0);
    if (t < 256) {
        unsigned long long v = nacc[t];
        int c = (int)(v >> 48);
        float nd = (float)(v & 0xFFFFFFFFFFFFULL) * 2.3283064365386963e-10f;
        float dv = rsqrtf(1.0f + nd);   // +1 self loop
        sdinv[t] = dv;
        if (t < nnodes) dinv[node0 + t] = dv;
        ncnt[t] = c;
        sscan[t] = c;
    }
    __syncthreads();
    for (int off = 1; off < 256; off <<= 1) {
        int u = (t >= off && t < 256) ? sscan[t - off] : 0;
        __syncthreads();
        if (t < 256) sscan[t] += u;
        __syncthreads();
    }
    if (t < nnodes) {
        int lbt = sscan[t] - ncnt[t];
        int s = bin * BINCAP + lbt;
        row_se[node0 + t] = make_int2(s, s + ncnt[t]);
    }
    if (t < 256) lb[t] = sscan[t] - ncnt[t];
    __syncthreads();
    // scale this bin's h rows by dinv (vectorized __half2, 4 B/lane)
    int nh = nnodes * 16;   // 16 half2 per table row
    __half2* pa = (__half2*)ha;
    __half2* pb = (__half2*)hb;
    for (int i = t; i < nh; i += 512) {
        int n = i >> 4;
        float dv = sdinv[n];
        int idx = node0 * 16 + i;
        float2 fa = __half22float2(pa[idx]);
        float2 fb = __half22float2(pb[idx]);
        pa[idx] = __floats2half2_rn(fa.x * dv, fa.y * dv);
        pb[idx] = __floats2half2_rn(fb.x * dv, fb.y * dv);
    }
    if (t < 256) ncnt[t] = 0;   // reuse as fill cursor
    __syncthreads();
    for (int i = t; i < cnt; i += 512) {
        unsigned long long ent = stage[i];
        unsigned int lo = (unsigned int)ent;
        int nl  = (lo >> 16) & 255;
        int src = lo & 0xFFFFu;
        float wm = __uint_as_float((unsigned int)(ent >> 32));
        int slot = atomicAdd(&ncnt[nl], 1);
        unsigned short wh = __half_as_ushort(__float2half_rn(wm));
        csr[bin * BINCAP + lb[nl] + slot] =
            (unsigned int)src | ((unsigned int)wh << 16);
    }
}

__device__ inline float hdec(unsigned int u) {
    return __half2float(__ushort_as_half((unsigned short)(u >> 16)));
}

// == gather (512 thr, R3/R7-verbatim): WIDE 16B/lane table reads (123->38us
// measured). cq=ln&3 picks a float4 (8 halves) of the 64B row; sg=ln>>2
// picks the edge -> 8 edges per load step, 4 lane-addresses/edge.
// BN stats: block LDS reduce -> atomics spread over NCOPY copies (R1 law:
// 128 addresses x 3125 serialized adds = +70us/launch; spread = free).
// out[d] = dd * ( sum_e wm_e * h'[s_e] + h'[d] ) + bias   (h' = dinv*h)
__global__ __launch_bounds__(512) void k_gather(const __half* __restrict__ ha,
                                                const __half* __restrict__ hb,
                                                const unsigned int* __restrict__ csr,
                                                const int2*  __restrict__ row_se,
                                                const float* __restrict__ dinv,
                                                const float* __restrict__ bias,
                                                float* __restrict__ out,
                                                float* __restrict__ stat) {
    __shared__ float s1[512], s2[512];
    int t = threadIdx.x;
    int half = blockIdx.x & 1;
    const float4* __restrict__ h4 = (const float4*)(half ? hb : ha);
    int node = (blockIdx.x >> 1) * 16 + (t >> 5);
    int ln = t & 31;
    int sg = ln >> 2;     // 0..7: edge subgroup
    int cq = ln & 3;      // 0..3: column quad (8 cols = 16B)
    int2 se = row_se[node];
    float dd = dinv[node];
    float acc[8];
    if (sg == 0) {        // self term (pre-scaled by dinv), added once
        float4 sv = h4[node * 4 + cq];
        const __half2* p = reinterpret_cast<const __half2*>(&sv);
#pragma unroll
        for (int i = 0; i < 4; ++i) {
            float2 f = __half22float2(p[i]);
            acc[2 * i] = f.x; acc[2 * i + 1] = f.y;
        }
    } else {
#pragma unroll
        for (int i = 0; i < 8; ++i) acc[i] = 0.0f;
    }
    for (int b = se.x; b < se.y; b += 32) {
        int c0 = min(32, se.y - b);
        int cm = c0 - 1;
        unsigned int my = (ln < c0) ? csr[b + ln] : 0u;
        // 4 masked steps x 8 edges; clamp keeps addresses valid, w=0 kills
        // the contribution. Poisson(32) degrees => <15% wasted slots.
        unsigned int u0 = __shfl(my, min(sg,      cm), 32);
        unsigned int u1 = __shfl(my, min(sg + 8,  cm), 32);
        unsigned int u2 = __shfl(my, min(sg + 16, cm), 32);
        unsigned int u3 = __shfl(my, min(sg + 24, cm), 32);
        float4 r0 = h4[(u0 & 0xFFFFu) * 4 + cq];
        float4 r1 = h4[(u1 & 0xFFFFu) * 4 + cq];
        float4 r2 = h4[(u2 & 0xFFFFu) * 4 + cq];
        float4 r3 = h4[(u3 & 0xFFFFu) * 4 + cq];
        float w0 = (sg      < c0) ? hdec(u0) : 0.0f;
        float w1 = (sg + 8  < c0) ? hdec(u1) : 0.0f;
        float w2 = (sg + 16 < c0) ? hdec(u2) : 0.0f;
        float w3 = (sg + 24 < c0) ? hdec(u3) : 0.0f;
        const __half2* p0 = reinterpret_cast<const __half2*>(&r0);
        const __half2* p1 = reinterpret_cast<const __half2*>(&r1);
        const __half2* p2 = reinterpret_cast<const __half2*>(&r2);
        const __half2* p3 = reinterpret_cast<const __half2*>(&r3);
#pragma unroll
        for (int i = 0; i < 4; ++i) {
            float2 f0 = __half22float2(p0[i]);
            float2 f1 = __half22float2(p1[i]);
            float2 f2 = __half22float2(p2[i]);
            float2 f3 = __half22float2(p3[i]);
            acc[2*i]   = fmaf(f0.x, w0, acc[2*i]);
            acc[2*i+1] = fmaf(f0.y, w0, acc[2*i+1]);
            acc[2*i]   = fmaf(f1.x, w1, acc[2*i]);
            acc[2*i+1] = fmaf(f1.y, w1, acc[2*i+1]);
            acc[2*i]   = fmaf(f2.x, w2, acc[2*i]);
            acc[2*i+1] = fmaf(f2.y, w2, acc[2*i+1]);
            acc[2*i]   = fmaf(f3.x, w3, acc[2*i]);
            acc[2*i+1] = fmaf(f3.y, w3, acc[2*i+1]);
        }
    }
    // fold 8 edge-subgroups (stride-4 lanes) -> lanes 0..3 hold 32 cols
#pragma unroll
    for (int off = 16; off >= 4; off >>= 1) {
#pragma unroll
        for (int i = 0; i < 8; ++i) acc[i] += __shfl_down(acc[i], off, 32);
    }
    if (ln < 4) {
        int col0 = half * 32 + cq * 8;
        float v[8];
#pragma unroll
        for (int i = 0; i < 8; ++i) v[i] = fmaf(acc[i], dd, bias[col0 + i]);
        float4* o = (float4*)out;
        o[node * 16 + half * 8 + cq * 2]     = make_float4(v[0], v[1], v[2], v[3]);
        o[node * 16 + half * 8 + cq * 2 + 1] = make_float4(v[4], v[5], v[6], v[7]);
        int lbx = (t >> 5) * 32 + cq * 8;
#pragma unroll
        for (int i = 0; i < 8; ++i) { s1[lbx + i] = v[i]; s2[lbx + i] = v[i] * v[i]; }
    }
    __syncthreads();
#pragma unroll
    for (int off = 256; off >= 32; off >>= 1) {
        if (t < off) { s1[t] += s1[t + off]; s2[t] += s2[t + off]; }
        __syncthreads();
    }
    if (t < 32) {
        int cp = (blockIdx.x >> 1) & (NCOPY - 1);
        int col = half * 32 + t;
        atomicAdd(&stat[cp * 128 + col],      s1[t]);
        atomicAdd(&stat[cp * 128 + 64 + col], s2[t]);
    }
}

// == GEMM2 fused BN1+ReLU in, dinv-scaled split fp16 out: [N,64]x[64,64] ====
// BN scale/shift computed inline from NCOPY-spread stat accumulators.
__global__ __launch_bounds__(256) void k_gemm2_bn(const float* __restrict__ hin,
                                                  const float* __restrict__ stat,
                                                  const float* __restrict__ gamma,
                                                  const float* __restrict__ beta,
                                                  const float* __restrict__ W,
                                                  const float* __restrict__ dinv,
                                                  __half* __restrict__ ha,
                                                  __half* __restrict__ hb) {
    __shared__ float sw[D_HID * D_HID];   // 16 KB
    __shared__ float sx[16 * D_HID];      // 4 KB
    __shared__ float sc[D_HID], sh[D_HID];
    int t = threadIdx.x;
    int row0 = blockIdx.x * 16;
#pragma unroll
    for (int j = 0; j < 16; ++j) sw[t + j * 256] = W[t + j * 256];
    if (t < 64) {
        float s = 0.0f, q = 0.0f;
#pragma unroll 8
        for (int c = 0; c < NCOPY; ++c) {
            s += stat[c * 128 + t];
            q += stat[c * 128 + 64 + t];
        }
        const float invn = 1.0f / (float)N_NODES;
        float mean = s * invn;
        float var  = q * invn - mean * mean;   // biased, = jnp.var
        float g    = gamma[t] * rsqrtf(var + BN_EPS);
        sc[t] = g;
        sh[t] = beta[t] - mean * g;
    }
    __syncthreads();
#pragma unroll
    for (int j = 0; j < 4; ++j) {
        int i = t + j * 256;
        int k = i & 63;
        sx[i] = fmaxf(0.0f, fmaf(hin[row0 * D_HID + i], sc[k], sh[k]));
    }
    __syncthreads();
    int c = t & 63, rg = (t >> 6) * 4;
    float a0 = 0, a1 = 0, a2 = 0, a3 = 0;
#pragma unroll 4
    for (int k = 0; k < D_HID; ++k) {
        float w = sw[k * D_HID + c];
        a0 = fmaf(sx[(rg + 0) * D_HID + k], w, a0);
        a1 = fmaf(sx[(rg + 1) * D_HID + k], w, a1);
        a2 = fmaf(sx[(rg + 2) * D_HID + k], w, a2);
        a3 = fmaf(sx[(rg + 3) * D_HID + k], w, a3);
    }
    __half* tbl = (c < 32) ? ha : hb;
    int cc = c & 31;
    tbl[(row0 + rg + 0) * 32 + cc] = __float2half_rn(a0 * dinv[row0 + rg + 0]);
    tbl[(row0 + rg + 1) * 32 + cc] = __float2half_rn(a1 * dinv[row0 + rg + 1]);
    tbl[(row0 + rg + 2) * 32 + cc] = __float2half_rn(a2 * dinv[row0 + rg + 2]);
    tbl[(row0 + rg + 3) * 32 + cc] = __float2half_rn(a3 * dinv[row0 + rg + 3]);
}

// ====== BN apply + ReLU (in place, float4); coeffs from spread stats =======
__global__ __launch_bounds__(256) void k_bn_apply_relu(float4* __restrict__ h,
                                                       const float* __restrict__ stat,
                                                       const float* __restrict__ gamma,
                                                       const float* __restrict__ beta) {
    __shared__ float sc[D_HID], sh[D_HID];
    int t = threadIdx.x;
    if (t < 64) {
        float s = 0.0f, q = 0.0f;
#pragma unroll 8
        for (int c = 0; c < NCOPY; ++c) {
            s += stat[c * 128 + t];
            q += stat[c * 128 + 64 + t];
        }
        const float invn = 1.0f / (float)N_NODES;
        float mean = s * invn;
        float var  = q * invn - mean * mean;
        float g    = gamma[t] * rsqrtf(var + BN_EPS);
        sc[t] = g;
        sh[t] = beta[t] - mean * g;
    }
    __syncthreads();
    int idx = blockIdx.x * 256 + t;
    if (idx >= N_NODES * D_HID / 4) return;
    int j = (idx & 15) * 4;
    float4 v = h[idx];
    v.x = fmaxf(0.0f, fmaf(v.x, sc[j],     sh[j]));
    v.y = fmaxf(0.0f, fmaf(v.y, sc[j + 1], sh[j + 1]));
    v.z = fmaxf(0.0f, fmaf(v.z, sc[j + 2], sh[j + 2]));
    v.w = fmaxf(0.0f, fmaf(v.w, sc[j + 3], sh[j + 3]));
    h[idx] = v;
}

extern "C" void kernel_launch(void* const* d_in, const int* in_sizes, int n_in,
                              void* d_out, int out_size, void* d_ws, size_t ws_size,
                              hipStream_t stream) {
    const float* x     = (const float*)d_in[0];
    const int*   ei_sc = (const int*)  d_in[1];   // [2*E] src then dst
    const float* w_sc  = (const float*)d_in[2];
    const float* w_fc  = (const float*)d_in[4];
    const float* alpha = (const float*)d_in[5];
    const float* W1    = (const float*)d_in[6];
    const float* b1    = (const float*)d_in[7];
    const float* W2    = (const float*)d_in[8];
    const float* b2    = (const float*)d_in[9];
    const float* g1    = (const float*)d_in[10];
    const float* be1   = (const float*)d_in[11];
    const float* g2    = (const float*)d_in[12];
    const float* be2   = (const float*)d_in[13];
    float* out = (float*)d_out;

    // ---- workspace layout, all segments 16B-aligned: ~40.1 MB
    // binned | row_se | bin_cur(256) | stats | dinv | csr | ha | hb | agg
    unsigned long long* binned = (unsigned long long*)d_ws;        // NBINS*BINCAP u64
    int2*  row_se  = (int2*)(binned + (size_t)NBINS * BINCAP);     // N int2
    int*   bin_cur = (int*)(row_se + N_NODES);                     // 256
    float* stats   = (float*)(bin_cur + NBINS);                    // 2*NCOPY*128
    float* dinv    = stats + 2 * NCOPY * 128;                      // N
    unsigned int* csr = (unsigned int*)(dinv + N_NODES);           // NBINS*BINCAP
    __half* ha     = (__half*)(csr + (size_t)NBINS * BINCAP);      // N*32 halves
    __half* hb     = ha + (size_t)N_NODES * 32;                    // N*32 halves
    float* agg     = (float*)(hb + (size_t)N_NODES * 32);          // N*64

    const int gV4 = (N_NODES * D_HID / 4 + 255) / 256;             // 3125
    const int gGA = NPAIR * 2;                                     // 6250
    const int gGM = N_NODES / 16;                                  // 3125

    // ---- fused binA+gemm1, then balanced CSR build (+dinv fold into h).
    // one memset covers bin_cur AND both layers' spread stat accumulators.
    hipMemsetAsync(bin_cur, 0, (NBINS + 2 * NCOPY * 128) * sizeof(int), stream);
    k_pre <<<256 + GEMM1B, 256, 0, stream>>>(w_sc, w_fc, ei_sc, alpha,
                                             bin_cur, binned, x, W1, ha, hb);
    k_binB<<<NBINS, 512, 0, stream>>>(bin_cur, binned, row_se, dinv, ha, hb, csr);

    // ---- layer 1 (BN stats spread-atomic accumulated in gather epilogue)
    k_gather  <<<gGA, 512, 0, stream>>>(ha, hb, csr, row_se, dinv, b1, agg, stats);

    // ---- layer 2 (BN1+ReLU coeffs computed inline; dinv folded into output)
    k_gemm2_bn<<<gGM, 256, 0, stream>>>(agg, stats, g1, be1, W2, dinv, ha, hb);
    k_gather  <<<gGA, 512, 0, stream>>>(ha, hb, csr, row_se, dinv, b2, out,
                                        stats + NCOPY * 128);
    k_bn_apply_relu<<<gV4, 256, 0, stream>>>((float4*)out, stats + NCOPY * 128,
                                             g2, be2);
}

// Round 11
// 270.052 us; speedup vs baseline: 1.2449x; 1.0061x over previous
//
#include <hip/hip_runtime.h>
#include <hip/hip_fp16.h>
#include <math.h>

#define N_NODES 50000
#define N_EDGES 1600000
#define D_INF   128
#define D_HID   64
#define BN_EPS  1e-5f
#define NBINS   256      // R10: 256 balanced bins (1 binB block per CU)
#define NPB     196      // nodes per bin (256*196 = 50176 >= N)
#define BINCAP  6912     // per-bin cap (mean 6250, +8.4 sigma)
#define EPB     6250     // edges per binA block (256 blocks x 6250 = E)
#define GEMM1B  3125     // gemm1 blocks inside k_pre
#define NPAIR   3125     // gather block-pairs (16 nodes each)
#define NCOPY   64       // BN stat accumulator copies (atomic spread)

// ============ fused k_pre: blocks 0..255 binA | 256..3380 gemm1 ============
// Ledger: reserved-contiguous-run binned writes are the density optimum
// (R4: direct scatter = 8x XCD write amp; R6: small bins = partial lines;
// R9: fixed slices = cross-XCD false sharing; R10: 196-node bins -> 195B
// runs, WRITE 27MB, best). R5: no grid.sync mega (phase regalloc + L2
// flush). R8: random-address device atomics cost ~32B HBM each.
struct SmGemm { float sw[D_INF * D_HID]; float sx[16 * D_INF]; };  // 40 KB
struct SmBin  { int hcnt[NBINS]; int hbase[NBINS]; };              // 2 KB
union SmPre { SmGemm g; SmBin a; };

__global__ __launch_bounds__(256) void k_pre(const float* __restrict__ wsc,
                                             const float* __restrict__ wfc,
                                             const int*   __restrict__ ei,
                                             const float* __restrict__ alpha,
                                             int* __restrict__ bin_cur,
                                             unsigned long long* __restrict__ binned,
                                             const float* __restrict__ x,
                                             const float* __restrict__ W,
                                             __half* __restrict__ ha,
                                             __half* __restrict__ hb) {
    __shared__ SmPre sm;
    int t = threadIdx.x;
    if (blockIdx.x < 256) {
        // ---------------- binA: bin edges by dst/196, staged coalesced -----
        int e0 = blockIdx.x * EPB;
        sm.a.hcnt[t] = 0;
        __syncthreads();
        for (int i = t; i < EPB; i += 256)
            atomicAdd(&sm.a.hcnt[(unsigned)ei[N_EDGES + e0 + i] / NPB], 1);
        __syncthreads();
        {
            int c = sm.a.hcnt[t];
            sm.a.hbase[t] = c ? atomicAdd(&bin_cur[t], c) : 0;
            sm.a.hcnt[t] = 0;
        }
        __syncthreads();
        float a = 1.0f / (1.0f + expf(-alpha[0]));
        for (int i = t; i < EPB; i += 256) {
            int e = e0 + i;
            int s = ei[e], d = ei[N_EDGES + e];
            float wm = fmaf(a, wsc[e] - wfc[e], wfc[e]);   // a*wsc+(1-a)*wfc
            int bin = (unsigned)d / NPB;
            int loc = d - bin * NPB;                       // 0..195, 8 bits
            int slot = atomicAdd(&sm.a.hcnt[bin], 1);
            int gpos = sm.a.hbase[bin] + slot;
            if (gpos < BINCAP) {
                unsigned long long ent =
                    ((unsigned long long)__float_as_uint(wm) << 32)
                    | (unsigned int)(s | (loc << 16));
                binned[(size_t)bin * BINCAP + gpos] = ent;
            }
        }
    } else {
        // ---------------- gemm1: [N,128]x[128,64] -> fp16 halves -----------
        int row0 = (blockIdx.x - 256) * 16;
#pragma unroll
        for (int j = 0; j < 32; ++j) sm.g.sw[t + j * 256] = W[t + j * 256];
#pragma unroll
        for (int j = 0; j < 8; ++j) {
            int i = t + j * 256;
            int r = i >> 7, k = i & 127;
            sm.g.sx[i] = x[(row0 + r) * D_INF + k];
        }
        __syncthreads();
        int c = t & 63, rg = (t >> 6) * 4;
        float a0 = 0, a1 = 0, a2 = 0, a3 = 0;
#pragma unroll 4
        for (int k = 0; k < D_INF; ++k) {
            float w = sm.g.sw[k * D_HID + c];
            a0 = fmaf(sm.g.sx[(rg + 0) * D_INF + k], w, a0);
            a1 = fmaf(sm.g.sx[(rg + 1) * D_INF + k], w, a1);
            a2 = fmaf(sm.g.sx[(rg + 2) * D_INF + k], w, a2);
            a3 = fmaf(sm.g.sx[(rg + 3) * D_INF + k], w, a3);
        }
        __half* tbl = (c < 32) ? ha : hb;
        int cc = c & 31;
        tbl[(row0 + rg + 0) * 32 + cc] = __float2half_rn(a0);
        tbl[(row0 + rg + 1) * 32 + cc] = __float2half_rn(a1);
        tbl[(row0 + rg + 2) * 32 + cc] = __float2half_rn(a2);
        tbl[(row0 + rg + 3) * 32 + cc] = __float2half_rn(a3);
    }
}

// ====== merged phase B (512 thr, 256 balanced blocks = 1/CU): LDS-stage
// entries once; packed-u64 hist -> dinv, row_se; scale h by dinv; fill csr.
// R7's one-atomic pass-1 (count<<48 | wm in 2^-32 fixed point; max
// 6912*2^32 = 2^44.8 < 2^48; ~1e-8 deg quantization). LDS ~62 KB.
__global__ __launch_bounds__(512) void k_binB(const int* __restrict__ bin_cur,
                                              const unsigned long long* __restrict__ binned,
                                              int2*  __restrict__ row_se,
                                              float* __restrict__ dinv,
                                              __half* __restrict__ ha,
                                              __half* __restrict__ hb,
                                              unsigned int* __restrict__ csr) {
    __shared__ unsigned long long stage[BINCAP];   // 55.3 KB
    __shared__ unsigned long long nacc[256];       // count<<48 | fixed ndeg
    __shared__ int   ncnt[256];
    __shared__ int   sscan[256];
    __shared__ float sdinv[256];
    __shared__ int   lb[256];
    int t = threadIdx.x;
    int bin = blockIdx.x;
    if (t < 256) nacc[t] = 0ULL;
    int cnt = min(bin_cur[bin], BINCAP);
    const unsigned long long* mybin = binned + (size_t)bin * BINCAP;
    for (int i = t; i < cnt; i += 512) stage[i] = mybin[i];
    __syncthreads();
    for (int i = t; i < cnt; i += 512) {
        unsigned long long ent = stage[i];
        unsigned int lo = (unsigned int)ent;
        int nl = (lo >> 16) & 255;
        float wm = __uint_as_float((unsigned int)(ent >> 32));
        unsigned long long pk = (1ULL << 48)
            | (unsigned long long)(wm * 4294967296.0f);
        atomicAdd(&nacc[nl], pk);
    }
    __syncthreads();
    int node0 = bin * NPB;
    int nnodes = min(NPB, N_NODES - node0);
    if (t < 256) {
        unsigned long long v = nacc[t];
        int c = (int)(v >> 48);
        float nd = (float)(v & 0xFFFFFFFFFFFFULL) * 2.3283064365386963e-10f;
        float dv = rsqrtf(1.0f + nd);   // +1 self loop
        sdinv[t] = dv;
        if (t < nnodes) dinv[node0 + t] = dv;
        ncnt[t] = c;
        sscan[t] = c;
    }
    __syncthreads();
    for (int off = 1; off < 256; off <<= 1) {
        int u = (t >= off && t < 256) ? sscan[t - off] : 0;
        __syncthreads();
        if (t < 256) sscan[t] += u;
        __syncthreads();
    }
    if (t < nnodes) {
        int lbt = sscan[t] - ncnt[t];
        int s = bin * BINCAP + lbt;
        row_se[node0 + t] = make_int2(s, s + ncnt[t]);
    }
    if (t < 256) lb[t] = sscan[t] - ncnt[t];
    __syncthreads();
    // scale this bin's h rows by dinv (vectorized __half2, 4 B/lane)
    int nh = nnodes * 16;   // 16 half2 per table row
    __half2* pa = (__half2*)ha;
    __half2* pb = (__half2*)hb;
    for (int i = t; i < nh; i += 512) {
        int n = i >> 4;
        float dv = sdinv[n];
        int idx = node0 * 16 + i;
        float2 fa = __half22float2(pa[idx]);
        float2 fb = __half22float2(pb[idx]);
        pa[idx] = __floats2half2_rn(fa.x * dv, fa.y * dv);
        pb[idx] = __floats2half2_rn(fb.x * dv, fb.y * dv);
    }
    if (t < 256) ncnt[t] = 0;   // reuse as fill cursor
    __syncthreads();
    for (int i = t; i < cnt; i += 512) {
        unsigned long long ent = stage[i];
        unsigned int lo = (unsigned int)ent;
        int nl  = (lo >> 16) & 255;
        int src = lo & 0xFFFFu;
        float wm = __uint_as_float((unsigned int)(ent >> 32));
        int slot = atomicAdd(&ncnt[nl], 1);
        unsigned short wh = __half_as_ushort(__float2half_rn(wm));
        csr[bin * BINCAP + lb[nl] + slot] =
            (unsigned int)src | ((unsigned int)wh << 16);
    }
}

__device__ inline float hdec(unsigned int u) {
    return __half2float(__ushort_as_half((unsigned short)(u >> 16)));
}

// == gather (512 thr): WIDE 16B/lane table reads (R3: 123->38us). R11:
// GUARDED batch steps -- Poisson(32) degrees mean ~46% of nodes have a
// 2nd batch with only ~4 real edges; the fixed 4-step form paid all 128
// lane-addresses anyway (w=0 kills value but not TA cost). Steps 1-3 now
// execute only if c0 > 8/16/24 (group-uniform branch; r zero-init keeps
// the unconditional FMA block NaN-safe; loads still issue before first
// use -> MLP preserved). Expected table lane-addrs -23%.
// BN stats: block LDS reduce -> atomics spread over NCOPY copies (R1 law).
// out[d] = dd * ( sum_e wm_e * h'[s_e] + h'[d] ) + bias   (h' = dinv*h)
__global__ __launch_bounds__(512) void k_gather(const __half* __restrict__ ha,
                                                const __half* __restrict__ hb,
                                                const unsigned int* __restrict__ csr,
                                                const int2*  __restrict__ row_se,
                                                const float* __restrict__ dinv,
                                                const float* __restrict__ bias,
                                                float* __restrict__ out,
                                                float* __restrict__ stat) {
    __shared__ float s1[512], s2[512];
    int t = threadIdx.x;
    int half = blockIdx.x & 1;
    const float4* __restrict__ h4 = (const float4*)(half ? hb : ha);
    int node = (blockIdx.x >> 1) * 16 + (t >> 5);
    int ln = t & 31;
    int sg = ln >> 2;     // 0..7: edge subgroup
    int cq = ln & 3;      // 0..3: column quad (8 cols = 16B)
    int2 se = row_se[node];
    float dd = dinv[node];
    float acc[8];
    if (sg == 0) {        // self term (pre-scaled by dinv), added once
        float4 sv = h4[node * 4 + cq];
        const __half2* p = reinterpret_cast<const __half2*>(&sv);
#pragma unroll
        for (int i = 0; i < 4; ++i) {
            float2 f = __half22float2(p[i]);
            acc[2 * i] = f.x; acc[2 * i + 1] = f.y;
        }
    } else {
#pragma unroll
        for (int i = 0; i < 8; ++i) acc[i] = 0.0f;
    }
    for (int b = se.x; b < se.y; b += 32) {
        int c0 = min(32, se.y - b);
        int cm = c0 - 1;
        unsigned int my = (ln < c0) ? csr[b + ln] : 0u;
        float4 r1 = make_float4(0.f, 0.f, 0.f, 0.f);
        float4 r2 = r1, r3 = r1;
        float w1 = 0.f, w2 = 0.f, w3 = 0.f;
        unsigned int u0 = __shfl(my, min(sg, cm), 32);
        float4 r0 = h4[(u0 & 0xFFFFu) * 4 + cq];
        float w0 = (sg < c0) ? hdec(u0) : 0.0f;
        if (c0 > 8) {
            unsigned int u1 = __shfl(my, min(sg + 8, cm), 32);
            r1 = h4[(u1 & 0xFFFFu) * 4 + cq];
            w1 = (sg + 8 < c0) ? hdec(u1) : 0.0f;
        }
        if (c0 > 16) {
            unsigned int u2 = __shfl(my, min(sg + 16, cm), 32);
            r2 = h4[(u2 & 0xFFFFu) * 4 + cq];
            w2 = (sg + 16 < c0) ? hdec(u2) : 0.0f;
        }
        if (c0 > 24) {
            unsigned int u3 = __shfl(my, min(sg + 24, cm), 32);
            r3 = h4[(u3 & 0xFFFFu) * 4 + cq];
            w3 = (sg + 24 < c0) ? hdec(u3) : 0.0f;
        }
        const __half2* p0 = reinterpret_cast<const __half2*>(&r0);
        const __half2* p1 = reinterpret_cast<const __half2*>(&r1);
        const __half2* p2 = reinterpret_cast<const __half2*>(&r2);
        const __half2* p3 = reinterpret_cast<const __half2*>(&r3);
#pragma unroll
        for (int i = 0; i < 4; ++i) {
            float2 f0 = __half22float2(p0[i]);
            float2 f1 = __half22float2(p1[i]);
            float2 f2 = __half22float2(p2[i]);
            float2 f3 = __half22float2(p3[i]);
            acc[2*i]   = fmaf(f0.x, w0, acc[2*i]);
            acc[2*i+1] = fmaf(f0.y, w0, acc[2*i+1]);
            acc[2*i]   = fmaf(f1.x, w1, acc[2*i]);
            acc[2*i+1] = fmaf(f1.y, w1, acc[2*i+1]);
            acc[2*i]   = fmaf(f2.x, w2, acc[2*i]);
            acc[2*i+1] = fmaf(f2.y, w2, acc[2*i+1]);
            acc[2*i]   = fmaf(f3.x, w3, acc[2*i]);
            acc[2*i+1] = fmaf(f3.y, w3, acc[2*i+1]);
        }
    }
    // fold 8 edge-subgroups (stride-4 lanes) -> lanes 0..3 hold 32 cols
#pragma unroll
    for (int off = 16; off >= 4; off >>= 1) {
#pragma unroll
        for (int i = 0; i < 8; ++i) acc[i] += __shfl_down(acc[i], off, 32);
    }
    if (ln < 4) {
        int col0 = half * 32 + cq * 8;
        float v[8];
#pragma unroll
        for (int i = 0; i < 8; ++i) v[i] = fmaf(acc[i], dd, bias[col0 + i]);
        float4* o = (float4*)out;
        o[node * 16 + half * 8 + cq * 2]     = make_float4(v[0], v[1], v[2], v[3]);
        o[node * 16 + half * 8 + cq * 2 + 1] = make_float4(v[4], v[5], v[6], v[7]);
        int lbx = (t >> 5) * 32 + cq * 8;
#pragma unroll
        for (int i = 0; i < 8; ++i) { s1[lbx + i] = v[i]; s2[lbx + i] = v[i] * v[i]; }
    }
    __syncthreads();
#pragma unroll
    for (int off = 256; off >= 32; off >>= 1) {
        if (t < off) { s1[t] += s1[t + off]; s2[t] += s2[t + off]; }
        __syncthreads();
    }
    if (t < 32) {
        int cp = (blockIdx.x >> 1) & (NCOPY - 1);
        int col = half * 32 + t;
        atomicAdd(&stat[cp * 128 + col],      s1[t]);
        atomicAdd(&stat[cp * 128 + 64 + col], s2[t]);
    }
}

// == GEMM2 fused BN1+ReLU in, dinv-scaled split fp16 out: [N,64]x[64,64] ====
// BN scale/shift computed inline from NCOPY-spread stat accumulators.
__global__ __launch_bounds__(256) void k_gemm2_bn(const float* __restrict__ hin,
                                                  const float* __restrict__ stat,
                                                  const float* __restrict__ gamma,
                                                  const float* __restrict__ beta,
                                                  const float* __restrict__ W,
                                                  const float* __restrict__ dinv,
                                                  __half* __restrict__ ha,
                                                  __half* __restrict__ hb) {
    __shared__ float sw[D_HID * D_HID];   // 16 KB
    __shared__ float sx[16 * D_HID];      // 4 KB
    __shared__ float sc[D_HID], sh[D_HID];
    int t = threadIdx.x;
    int row0 = blockIdx.x * 16;
#pragma unroll
    for (int j = 0; j < 16; ++j) sw[t + j * 256] = W[t + j * 256];
    if (t < 64) {
        float s = 0.0f, q = 0.0f;
#pragma unroll 8
        for (int c = 0; c < NCOPY; ++c) {
            s += stat[c * 128 + t];
            q += stat[c * 128 + 64 + t];
        }
        const float invn = 1.0f / (float)N_NODES;
        float mean = s * invn;
        float var  = q * invn - mean * mean;   // biased, = jnp.var
        float g    = gamma[t] * rsqrtf(var + BN_EPS);
        sc[t] = g;
        sh[t] = beta[t] - mean * g;
    }
    __syncthreads();
#pragma unroll
    for (int j = 0; j < 4; ++j) {
        int i = t + j * 256;
        int k = i & 63;
        sx[i] = fmaxf(0.0f, fmaf(hin[row0 * D_HID + i], sc[k], sh[k]));
    }
    __syncthreads();
    int c = t & 63, rg = (t >> 6) * 4;
    float a0 = 0, a1 = 0, a2 = 0, a3 = 0;
#pragma unroll 4
    for (int k = 0; k < D_HID; ++k) {
        float w = sw[k * D_HID + c];
        a0 = fmaf(sx[(rg + 0) * D_HID + k], w, a0);
        a1 = fmaf(sx[(rg + 1) * D_HID + k], w, a1);
        a2 = fmaf(sx[(rg + 2) * D_HID + k], w, a2);
        a3 = fmaf(sx[(rg + 3) * D_HID + k], w, a3);
    }
    __half* tbl = (c < 32) ? ha : hb;
    int cc = c & 31;
    tbl[(row0 + rg + 0) * 32 + cc] = __float2half_rn(a0 * dinv[row0 + rg + 0]);
    tbl[(row0 + rg + 1) * 32 + cc] = __float2half_rn(a1 * dinv[row0 + rg + 1]);
    tbl[(row0 + rg + 2) * 32 + cc] = __float2half_rn(a2 * dinv[row0 + rg + 2]);
    tbl[(row0 + rg + 3) * 32 + cc] = __float2half_rn(a3 * dinv[row0 + rg + 3]);
}

// ====== BN apply + ReLU (in place, float4); coeffs from spread stats =======
__global__ __launch_bounds__(256) void k_bn_apply_relu(float4* __restrict__ h,
                                                       const float* __restrict__ stat,
                                                       const float* __restrict__ gamma,
                                                       const float* __restrict__ beta) {
    __shared__ float sc[D_HID], sh[D_HID];
    int t = threadIdx.x;
    if (t < 64) {
        float s = 0.0f, q = 0.0f;
#pragma unroll 8
        for (int c = 0; c < NCOPY; ++c) {
            s += stat[c * 128 + t];
            q += stat[c * 128 + 64 + t];
        }
        const float invn = 1.0f / (float)N_NODES;
        float mean = s * invn;
        float var  = q * invn - mean * mean;
        float g    = gamma[t] * rsqrtf(var + BN_EPS);
        sc[t] = g;
        sh[t] = beta[t] - mean * g;
    }
    __syncthreads();
    int idx = blockIdx.x * 256 + t;
    if (idx >= N_NODES * D_HID / 4) return;
    int j = (idx & 15) * 4;
    float4 v = h[idx];
    v.x = fmaxf(0.0f, fmaf(v.x, sc[j],     sh[j]));
    v.y = fmaxf(0.0f, fmaf(v.y, sc[j + 1], sh[j + 1]));
    v.z = fmaxf(0.0f, fmaf(v.z, sc[j + 2], sh[j + 2]));
    v.w = fmaxf(0.0f, fmaf(v.w, sc[j + 3], sh[j + 3]));
    h[idx] = v;
}

extern "C" void kernel_launch(void* const* d_in, const int* in_sizes, int n_in,
                              void* d_out, int out_size, void* d_ws, size_t ws_size,
                              hipStream_t stream) {
    const float* x     = (const float*)d_in[0];
    const int*   ei_sc = (const int*)  d_in[1];   // [2*E] src then dst
    const float* w_sc  = (const float*)d_in[2];
    const float* w_fc  = (const float*)d_in[4];
    const float* alpha = (const float*)d_in[5];
    const float* W1    = (const float*)d_in[6];
    const float* b1    = (const float*)d_in[7];
    const float* W2    = (const float*)d_in[8];
    const float* b2    = (const float*)d_in[9];
    const float* g1    = (const float*)d_in[10];
    const float* be1   = (const float*)d_in[11];
    const float* g2    = (const float*)d_in[12];
    const float* be2   = (const float*)d_in[13];
    float* out = (float*)d_out;

    // ---- workspace layout, all segments 16B-aligned: ~40.1 MB
    // binned | row_se | bin_cur(256) | stats | dinv | csr | ha | hb | agg
    unsigned long long* binned = (unsigned long long*)d_ws;        // NBINS*BINCAP u64
    int2*  row_se  = (int2*)(binned + (size_t)NBINS * BINCAP);     // N int2
    int*   bin_cur = (int*)(row_se + N_NODES);                     // 256
    float* stats   = (float*)(bin_cur + NBINS);                    // 2*NCOPY*128
    float* dinv    = stats + 2 * NCOPY * 128;                      // N
    unsigned int* csr = (unsigned int*)(dinv + N_NODES);           // NBINS*BINCAP
    __half* ha     = (__half*)(csr + (size_t)NBINS * BINCAP);      // N*32 halves
    __half* hb     = ha + (size_t)N_NODES * 32;                    // N*32 halves
    float* agg     = (float*)(hb + (size_t)N_NODES * 32);          // N*64

    const int gV4 = (N_NODES * D_HID / 4 + 255) / 256;             // 3125
    const int gGA = NPAIR * 2;                                     // 6250
    const int gGM = N_NODES / 16;                                  // 3125

    // ---- fused binA+gemm1, then balanced CSR build (+dinv fold into h).
    // one memset covers bin_cur AND both layers' spread stat accumulators.
    hipMemsetAsync(bin_cur, 0, (NBINS + 2 * NCOPY * 128) * sizeof(int), stream);
    k_pre <<<256 + GEMM1B, 256, 0, stream>>>(w_sc, w_fc, ei_sc, alpha,
                                             bin_cur, binned, x, W1, ha, hb);
    k_binB<<<NBINS, 512, 0, stream>>>(bin_cur, binned, row_se, dinv, ha, hb, csr);

    // ---- layer 1 (BN stats spread-atomic accumulated in gather epilogue)
    k_gather  <<<gGA, 512, 0, stream>>>(ha, hb, csr, row_se, dinv, b1, agg, stats);

    // ---- layer 2 (BN1+ReLU coeffs computed inline; dinv folded into output)
    k_gemm2_bn<<<gGM, 256, 0, stream>>>(agg, stats, g1, be1, W2, dinv, ha, hb);
    k_gather  <<<gGA, 512, 0, stream>>>(ha, hb, csr, row_se, dinv, b2, out,
                                        stats + NCOPY * 128);
    k_bn_apply_relu<<<gV4, 256, 0, stream>>>((float4*)out, stats + NCOPY * 128,
                                             g2, be2);
}